// Round 2
// baseline (1254.527 us; speedup 1.0000x reference)
//
#include <hip/hip_runtime.h>
#include <hip/hip_bf16.h>

typedef short short8 __attribute__((ext_vector_type(8)));
typedef float f32x4 __attribute__((ext_vector_type(4)));

#define NROWS 16384
#define UNITS 1024

__device__ __forceinline__ unsigned short f2bf(float x) {
    union { float f; unsigned int u; } v; v.f = x;
    unsigned int r = v.u + 0x7fffu + ((v.u >> 16) & 1u);
    return (unsigned short)(r >> 16);
}
__device__ __forceinline__ float bf2f(unsigned short h) {
    union { unsigned int u; float f; } v; v.u = ((unsigned int)h) << 16; return v.f;
}

// ---------------- prep: transpose weights [K x N] -> BT [N x K], split bf16 hi/lo ----------------
struct TrArgs {
    const float* src[8];
    unsigned short* dh[8];
    unsigned short* dl[8];
};

__global__ void transpose_split(TrArgs args) {
    __shared__ float t[32][33];
    const float* src = args.src[blockIdx.z];
    unsigned short* dh = args.dh[blockIdx.z];
    unsigned short* dl = args.dl[blockIdx.z];
    const int tx = threadIdx.x, ty = threadIdx.y;
    const int bk = blockIdx.y * 32, bn = blockIdx.x * 32;
#pragma unroll
    for (int q = 0; q < 4; ++q)
        t[ty + q * 8][tx] = src[(size_t)(bk + ty + q * 8) * UNITS + bn + tx];
    __syncthreads();
#pragma unroll
    for (int q = 0; q < 4; ++q) {
        float v = t[tx][ty + q * 8];
        unsigned short h = f2bf(v);
        size_t o = (size_t)(bn + ty + q * 8) * UNITS + bk + tx;
        dh[o] = h;
        dl[o] = f2bf(v - bf2f(h));
    }
}

// ---------------- main GEMM: C = [A0|A1](fp32) @ [B0;B1]^T via bf16 hi/lo 3-term split ----------
// A0/A1: [16384 x 1024] fp32 row-major (split to bf16 hi/lo in-register at staging).
// B*h/B*l: [NCOL x 1024] bf16 row-major (pre-transposed, pre-split).
struct GArgs {
    const float* A0;
    const float* A1;
    const unsigned short* B0h; const unsigned short* B0l;
    const unsigned short* B1h; const unsigned short* B1l;
};

template <int EPI>
__global__ __launch_bounds__(256) void gemm_hl(
    GArgs g, const float* __restrict__ Sin,
    const float* __restrict__ bias0, const float* __restrict__ bias1, const float* __restrict__ bias2,
    float* __restrict__ outZ,   // d_out: Z for EPI=1, final S_new for EPI=2
    float* __restrict__ Gws, float* __restrict__ SR) {
    __shared__ __align__(16) unsigned short Ah[128][64];   // 16 KB each
    __shared__ __align__(16) unsigned short Al[128][64];
    __shared__ __align__(16) unsigned short Bh[128][64];
    __shared__ __align__(16) unsigned short Bl[128][64];
    const int tid = threadIdx.x;
    const int wave = tid >> 6, lane = tid & 63;
    const int row0 = blockIdx.y * 128;
    const int col0 = blockIdx.x * 128;

    f32x4 acc[4][4] = {};

    const int arow = tid >> 4;           // 0..15 (A staging row base)
    const int acol = (tid & 15) * 4;     // fp32 col within 64-wide K slice
    const int brow = lane >> 3;          // B staging row within 8-row chunk
    const int bcol = (lane & 7) * 8;     // bf16 col (16 B per lane)
    const int frow = lane & 15;
    const int fk = (lane >> 4) * 8;
    const int wr = (wave >> 1) * 64;
    const int wc = (wave & 1) * 64;

    for (int t = 0; t < 32; ++t) {       // 2 halves (A0/A1) x 16 K-tiles of 64
        const int half = t >> 4;
        const int k0 = (t & 15) * 64;
        const float* Ag = (half ? g.A1 : g.A0) + (size_t)row0 * 1024 + k0;
        const unsigned short* Bgh = (half ? g.B1h : g.B0h) + (size_t)col0 * 1024 + k0;
        const unsigned short* Bgl = (half ? g.B1l : g.B0l) + (size_t)col0 * 1024 + k0;

        // 1) A fp32 tile -> registers (issue first so its vmcnt wait leaves B in flight)
        float4 av[8];
#pragma unroll
        for (int l = 0; l < 8; ++l)
            av[l] = *reinterpret_cast<const float4*>(Ag + (size_t)(l * 16 + arow) * 1024 + acol);
        // 2) B hi/lo -> LDS via async global_load_lds (wave-uniform dest base + lane*16)
#pragma unroll
        for (int q = 0; q < 4; ++q) {
            const int c = wave * 4 + q;
            const int r = c * 8 + brow;
            __builtin_amdgcn_global_load_lds(
                (const __attribute__((address_space(1))) unsigned int*)(Bgh + (size_t)r * 1024 + bcol),
                (__attribute__((address_space(3))) unsigned int*)((char*)&Bh[0][0] + c * 1024), 16, 0, 0);
            __builtin_amdgcn_global_load_lds(
                (const __attribute__((address_space(1))) unsigned int*)(Bgl + (size_t)r * 1024 + bcol),
                (__attribute__((address_space(3))) unsigned int*)((char*)&Bl[0][0] + c * 1024), 16, 0, 0);
        }
        // 3) split A to bf16 hi/lo, write both LDS planes
#pragma unroll
        for (int l = 0; l < 8; ++l) {
            const int r = l * 16 + arow;
            float4 v = av[l];
            ushort4 h, lo;
            h.x = f2bf(v.x); lo.x = f2bf(v.x - bf2f(h.x));
            h.y = f2bf(v.y); lo.y = f2bf(v.y - bf2f(h.y));
            h.z = f2bf(v.z); lo.z = f2bf(v.z - bf2f(h.z));
            h.w = f2bf(v.w); lo.w = f2bf(v.w - bf2f(h.w));
            *reinterpret_cast<ushort4*>(&Ah[r][acol]) = h;
            *reinterpret_cast<ushort4*>(&Al[r][acol]) = lo;
        }
        __syncthreads();   // drains global_load_lds (vmcnt) + ds_writes (lgkm)
        // 4) fragments + 3-term MFMA
#pragma unroll
        for (int kk = 0; kk < 2; ++kk) {
            short8 fah[4], fal[4], fbh[4], fbl[4];
#pragma unroll
            for (int m = 0; m < 4; ++m) {
                fah[m] = *reinterpret_cast<const short8*>(&Ah[wr + m * 16 + frow][kk * 32 + fk]);
                fal[m] = *reinterpret_cast<const short8*>(&Al[wr + m * 16 + frow][kk * 32 + fk]);
            }
#pragma unroll
            for (int n = 0; n < 4; ++n) {
                fbh[n] = *reinterpret_cast<const short8*>(&Bh[wc + n * 16 + frow][kk * 32 + fk]);
                fbl[n] = *reinterpret_cast<const short8*>(&Bl[wc + n * 16 + frow][kk * 32 + fk]);
            }
#pragma unroll
            for (int m = 0; m < 4; ++m)
#pragma unroll
                for (int n = 0; n < 4; ++n) {
                    acc[m][n] = __builtin_amdgcn_mfma_f32_16x16x32_bf16(fah[m], fbh[n], acc[m][n], 0, 0, 0);
                    acc[m][n] = __builtin_amdgcn_mfma_f32_16x16x32_bf16(fal[m], fbh[n], acc[m][n], 0, 0, 0);
                    acc[m][n] = __builtin_amdgcn_mfma_f32_16x16x32_bf16(fah[m], fbl[n], acc[m][n], 0, 0, 0);
                }
        }
        __syncthreads();
    }

    // epilogue: C/D layout col=lane&15, row=(lane>>4)*4+j  [m89-verified]
#pragma unroll
    for (int m = 0; m < 4; ++m)
#pragma unroll
        for (int n = 0; n < 4; ++n)
#pragma unroll
            for (int j = 0; j < 4; ++j) {
                const int row = row0 + wr + m * 16 + (lane >> 4) * 4 + j;
                const int col = col0 + wc + n * 16 + (lane & 15);
                float v = acc[m][n][j];
                if (EPI == 1) {
                    const int gate = col >> 10;       // 0:Z 1:G 2:R (uniform per block)
                    const int c = col & 1023;
                    const size_t ix = (size_t)row * UNITS + c;
                    if (gate == 0) {
                        outZ[ix] = tanhf(v + bias0[c]);
                    } else if (gate == 1) {
                        Gws[ix] = tanhf(v + bias1[c]);
                    } else {
                        SR[ix] = Sin[ix] * tanhf(v + bias2[c]);
                    }
                } else {
                    const size_t ix = (size_t)row * UNITS + col;
                    float h = tanhf(v + bias0[col]);
                    float z = outZ[ix];
                    float gg = Gws[ix];
                    float s = Sin[ix];
                    outZ[ix] = (1.0f - gg) * h + z * s;   // same-thread read-then-write: no race
                }
            }
}

extern "C" void kernel_launch(void* const* d_in, const int* in_sizes, int n_in,
                              void* d_out, int out_size, void* d_ws, size_t ws_size,
                              hipStream_t stream) {
    const float* X  = (const float*)d_in[0];
    const float* S  = (const float*)d_in[1];
    const float* Uz = (const float*)d_in[2];
    const float* Ug = (const float*)d_in[3];
    const float* Ur = (const float*)d_in[4];
    const float* Uh = (const float*)d_in[5];
    const float* Wz = (const float*)d_in[6];
    const float* Wg = (const float*)d_in[7];
    const float* Wr = (const float*)d_in[8];
    const float* Wh = (const float*)d_in[9];
    const float* bz = (const float*)d_in[10];
    const float* bg = (const float*)d_in[11];
    const float* br = (const float*)d_in[12];
    const float* bh = (const float*)d_in[13];
    float* out = (float*)d_out;

    // workspace carve: 160 MiB total
    const size_t SZ_PLANE = (size_t)NROWS * UNITS * 4;      // 64 MiB fp32 plane
    const size_t SZ_W3 = (size_t)3072 * 1024 * 2;           // 6 MiB bf16 plane
    const size_t SZ_W1 = (size_t)1024 * 1024 * 2;           // 2 MiB bf16 plane
    const size_t need = 2 * SZ_PLANE + 4 * SZ_W3 + 4 * SZ_W1;
    if (ws_size < need) return;   // fail loudly (poisoned d_out) instead of faulting

    char* w = (char*)d_ws;
    float* SR = (float*)w;          w += SZ_PLANE;
    float* G  = (float*)w;          w += SZ_PLANE;
    unsigned short* BTU_h  = (unsigned short*)w; w += SZ_W3;
    unsigned short* BTU_l  = (unsigned short*)w; w += SZ_W3;
    unsigned short* BTW_h  = (unsigned short*)w; w += SZ_W3;
    unsigned short* BTW_l  = (unsigned short*)w; w += SZ_W3;
    unsigned short* BTUh_h = (unsigned short*)w; w += SZ_W1;
    unsigned short* BTUh_l = (unsigned short*)w; w += SZ_W1;
    unsigned short* BTWh_h = (unsigned short*)w; w += SZ_W1;
    unsigned short* BTWh_l = (unsigned short*)w; w += SZ_W1;

    TrArgs ta;
    const size_t seg = (size_t)1024 * 1024;
    ta.src[0] = Uz; ta.dh[0] = BTU_h;            ta.dl[0] = BTU_l;
    ta.src[1] = Ug; ta.dh[1] = BTU_h + seg;      ta.dl[1] = BTU_l + seg;
    ta.src[2] = Ur; ta.dh[2] = BTU_h + 2 * seg;  ta.dl[2] = BTU_l + 2 * seg;
    ta.src[3] = Wz; ta.dh[3] = BTW_h;            ta.dl[3] = BTW_l;
    ta.src[4] = Wg; ta.dh[4] = BTW_h + seg;      ta.dl[4] = BTW_l + seg;
    ta.src[5] = Wr; ta.dh[5] = BTW_h + 2 * seg;  ta.dl[5] = BTW_l + 2 * seg;
    ta.src[6] = Uh; ta.dh[6] = BTUh_h;           ta.dl[6] = BTUh_l;
    ta.src[7] = Wh; ta.dh[7] = BTWh_h;           ta.dl[7] = BTWh_l;
    transpose_split<<<dim3(32, 32, 8), dim3(32, 8), 0, stream>>>(ta);

    // GEMM1: zgr = tanh(X@U_zgr + S@W_zgr + b); Z->out, G->ws, SR=S*tanh(R)->ws (fp32)
    GArgs g1;
    g1.A0 = X; g1.A1 = S;
    g1.B0h = BTU_h; g1.B0l = BTU_l; g1.B1h = BTW_h; g1.B1l = BTW_l;
    gemm_hl<1><<<dim3(24, 128), 256, 0, stream>>>(g1, S, bz, bg, br, out, G, SR);

    // GEMM2: H = tanh(X@Uh + SR@Wh + bh); S_new = (1-G)*H + Z*S
    GArgs g2;
    g2.A0 = X; g2.A1 = SR;
    g2.B0h = BTUh_h; g2.B0l = BTUh_l; g2.B1h = BTWh_h; g2.B1l = BTWh_l;
    gemm_hl<2><<<dim3(8, 128), 256, 0, stream>>>(g2, S, bh, nullptr, nullptr, out, G, SR);
}

// Round 8
// 1120.806 us; speedup vs baseline: 1.1193x; 1.1193x over previous
//
#include <hip/hip_runtime.h>
#include <hip/hip_bf16.h>

typedef short short8 __attribute__((ext_vector_type(8)));
typedef unsigned short ushort8 __attribute__((ext_vector_type(8)));
typedef float f32x4 __attribute__((ext_vector_type(4)));

#define NROWS 16384
#define UNITS 1024

__device__ __forceinline__ unsigned short f2bf(float x) {
    union { float f; unsigned int u; } v; v.f = x;
    unsigned int r = v.u + 0x7fffu + ((v.u >> 16) & 1u);
    return (unsigned short)(r >> 16);
}
__device__ __forceinline__ float bf2f(unsigned short h) {
    union { unsigned int u; float f; } v; v.u = ((unsigned int)h) << 16; return v.f;
}

// ---------------- prep 1: transpose weights [K x N] -> BT [N x K], split bf16 hi/lo --------
struct TrArgs {
    const float* src[8];
    unsigned short* dh[8];
    unsigned short* dl[8];
};

__global__ void transpose_split(TrArgs args) {
    __shared__ float t[32][33];
    const float* src = args.src[blockIdx.z];
    unsigned short* dh = args.dh[blockIdx.z];
    unsigned short* dl = args.dl[blockIdx.z];
    const int tx = threadIdx.x, ty = threadIdx.y;
    const int bk = blockIdx.y * 32, bn = blockIdx.x * 32;
#pragma unroll
    for (int q = 0; q < 4; ++q)
        t[ty + q * 8][tx] = src[(size_t)(bk + ty + q * 8) * UNITS + bn + tx];
    __syncthreads();
#pragma unroll
    for (int q = 0; q < 4; ++q) {
        float v = t[tx][ty + q * 8];
        unsigned short h = f2bf(v);
        size_t o = (size_t)(bn + ty + q * 8) * UNITS + bk + tx;
        dh[o] = h;
        dl[o] = f2bf(v - bf2f(h));
    }
}

// ---------------- prep 2: build swizzled per-(colblock,ktile) staging images ----------------
// Image elem layout: [tile][c(256)][q'(4)][e(8)], holding BT[cb*256+c][k0 + (q'^((c>>1)&3))*8 + e].
// global_load_lds then copies image bytes linearly into LDS; reads apply the same XOR.
__global__ void img_perm_k(const unsigned short* __restrict__ BT0h, const unsigned short* __restrict__ BT0l,
                           const unsigned short* __restrict__ BT1h, const unsigned short* __restrict__ BT1l,
                           unsigned short* __restrict__ imgH, unsigned short* __restrict__ imgL) {
    const int g = blockIdx.x * blockDim.x + threadIdx.x;   // one 16B chunk per thread
    const int tile = g >> 10;
    const int c = (g >> 2) & 255;
    const int qp = g & 3;
    const int cb = tile >> 6, kt = tile & 63;
    const int col = cb * 256 + c;
    const int kin = (qp ^ ((c >> 1) & 3)) * 8;
    const unsigned short* sh;
    const unsigned short* sl;
    int k0;
    if (kt < 32) { sh = BT0h; sl = BT0l; k0 = kt * 32; }
    else         { sh = BT1h; sl = BT1l; k0 = (kt - 32) * 32; }
    const size_t so = (size_t)col * 1024 + k0 + kin;
    *reinterpret_cast<ushort8*>(imgH + (size_t)g * 8) = *reinterpret_cast<const ushort8*>(sh + so);
    *reinterpret_cast<ushort8*>(imgL + (size_t)g * 8) = *reinterpret_cast<const ushort8*>(sl + so);
}

// ---------------- main GEMM: 256x256 tile, BK=32, 8 waves, 4-phase counted-vmcnt pipeline ----
// C = [A0|A1](fp32) @ B^T via bf16 hi/lo 3-term split. B from pre-swizzled images.
template <int EPI>
__global__ __launch_bounds__(512, 2) void gemm8(
    const float* __restrict__ A0, const float* __restrict__ A1,
    const unsigned short* __restrict__ imgH, const unsigned short* __restrict__ imgL,
    const float* __restrict__ Sin,
    const float* __restrict__ b0, const float* __restrict__ b1, const float* __restrict__ b2,
    float* __restrict__ outZ, float* __restrict__ Gws, float* __restrict__ SR) {
    // LDS: 2 buffers x {Ah,Al,Bh,Bl} x 16 KB = 128 KiB
    __shared__ __align__(16) char lds[131072];

    const int tid = threadIdx.x;
    const int wave = tid >> 6, lane = tid & 63;
    const int wM = wave >> 2, wN = wave & 3;          // 2 x 4 wave grid; wave owns 128x64
    const int fr = lane & 15, fq = lane >> 4;
    const int sA = ((fq ^ ((fr >> 1) & 3)) << 4);     // swizzled chunk byte offset (read side)
    const int arow = tid >> 1, ahalf = tid & 1;       // A staging: 2 threads/row
    const int awsz = (tid >> 2) & 3;                  // (arow>>1)&3

    // XCD-aware block swizzle (grid % 8 == 0 for both GEMMs)
    const int nwg = gridDim.x;
    const int w = (blockIdx.x & 7) * (nwg >> 3) + (blockIdx.x >> 3);
    const int cb = w >> 6;          // col block (B panel) — consecutive w share it
    const int rb = w & 63;          // row block
    const int row0 = rb * 256;
    const int col0 = cb * 256;

    f32x4 acc[8][4] = {};
    float4 av[4];                   // in-flight A fp32 regs (one tile)

    auto issueA = [&](int ts) {
        const float* Ag = (ts < 32 ? A0 : A1) + (size_t)(row0 + arow) * 1024 + (ts & 31) * 32 + ahalf * 16;
        av[0] = *reinterpret_cast<const float4*>(Ag);
        av[1] = *reinterpret_cast<const float4*>(Ag + 4);
        av[2] = *reinterpret_cast<const float4*>(Ag + 8);
        av[3] = *reinterpret_cast<const float4*>(Ag + 12);
    };
    auto issueB = [&](int ts, int buf, int pl) {      // 2 gload_lds per wave per plane
        const unsigned short* img = (pl ? imgL : imgH) + ((size_t)(cb * 64 + ts)) * 8192;
#pragma unroll
        for (int i = 0; i < 2; ++i) {
            const unsigned short* src = img + (wave * 2 + i) * 512 + lane * 8;
            char* dst = lds + (buf << 16) + 32768 + pl * 16384 + (wave * 2 + i) * 1024;
            __builtin_amdgcn_global_load_lds(
                (const __attribute__((address_space(1))) unsigned int*)src,
                (__attribute__((address_space(3))) unsigned int*)dst, 16, 0, 0);
        }
    };
    auto writeA = [&](int buf) {                      // cvt fp32 -> hi/lo, swizzled ds_write
        ushort8 h0, h1, l0, l1;
#pragma unroll
        for (int j = 0; j < 2; ++j) {
            float4 v = av[j];
            h0[j * 4 + 0] = f2bf(v.x); l0[j * 4 + 0] = f2bf(v.x - bf2f(h0[j * 4 + 0]));
            h0[j * 4 + 1] = f2bf(v.y); l0[j * 4 + 1] = f2bf(v.y - bf2f(h0[j * 4 + 1]));
            h0[j * 4 + 2] = f2bf(v.z); l0[j * 4 + 2] = f2bf(v.z - bf2f(h0[j * 4 + 2]));
            h0[j * 4 + 3] = f2bf(v.w); l0[j * 4 + 3] = f2bf(v.w - bf2f(h0[j * 4 + 3]));
        }
#pragma unroll
        for (int j = 0; j < 2; ++j) {
            float4 v = av[2 + j];
            h1[j * 4 + 0] = f2bf(v.x); l1[j * 4 + 0] = f2bf(v.x - bf2f(h1[j * 4 + 0]));
            h1[j * 4 + 1] = f2bf(v.y); l1[j * 4 + 1] = f2bf(v.y - bf2f(h1[j * 4 + 1]));
            h1[j * 4 + 2] = f2bf(v.z); l1[j * 4 + 2] = f2bf(v.z - bf2f(h1[j * 4 + 2]));
            h1[j * 4 + 3] = f2bf(v.w); l1[j * 4 + 3] = f2bf(v.w - bf2f(h1[j * 4 + 3]));
        }
        const int q0 = (2 * ahalf) ^ awsz;
        const int q1 = (2 * ahalf + 1) ^ awsz;
        char* db = lds + (buf << 16) + arow * 64;
        *reinterpret_cast<ushort8*>(db + (q0 << 4)) = h0;
        *reinterpret_cast<ushort8*>(db + (q1 << 4)) = h1;
        *reinterpret_cast<ushort8*>(db + 16384 + (q0 << 4)) = l0;
        *reinterpret_cast<ushort8*>(db + 16384 + (q1 << 4)) = l1;
    };

    // ---- prologue: stage tile 0, issue A(1); leaves [A(1):4] in flight ----
    issueA(0);
    issueB(0, 0, 0);
    issueB(0, 0, 1);
    asm volatile("s_waitcnt vmcnt(4)" ::: "memory");   // A(0) arrived (B(0) in flight)
    writeA(0);
    issueA(1);
    asm volatile("s_waitcnt vmcnt(4) lgkmcnt(0)" ::: "memory");  // B(0) done; A-writes drained
    __builtin_amdgcn_s_barrier();

    // ---- main loop: 64 K-tiles of 32 (K = 2x1024), 4 phases each ----
    for (int t = 0; t < 64; ++t) {
        const int cur = t & 1, nxt = cur ^ 1;
        const int tp1 = (t + 1 < 64) ? t + 1 : 0;      // dummy-alias tile 0 past the end
        const int tp2 = (t + 2 < 64) ? t + 2 : 0;
        const char* base = lds + (cur << 16);
#pragma unroll
        for (int p = 0; p < 4; ++p) {
            const int mh = p >> 1, nh = p & 1;         // C-quadrant
            short8 fah[4], fal[4], fbh[2], fbl[2];
#pragma unroll
            for (int mi = 0; mi < 4; ++mi) {
                const int off = (wM * 128 + (mh * 4 + mi) * 16 + fr) * 64 + sA;
                fah[mi] = *reinterpret_cast<const short8*>(base + off);
                fal[mi] = *reinterpret_cast<const short8*>(base + 16384 + off);
            }
#pragma unroll
            for (int ni = 0; ni < 2; ++ni) {
                const int off = (wN * 64 + (nh * 2 + ni) * 16 + fr) * 64 + sA;
                fbh[ni] = *reinterpret_cast<const short8*>(base + 32768 + off);
                fbl[ni] = *reinterpret_cast<const short8*>(base + 49152 + off);
            }
            // staging slice for this phase (counted-vmcnt ledger; see header comment)
            if (p == 0) issueB(tp1, nxt, 0);                       // vm: 4 -> 6
            if (p == 1) issueB(tp1, nxt, 1);                       // vm: 6 -> 8
            if (p == 2) {
                asm volatile("s_waitcnt vmcnt(4)" ::: "memory");   // A(t+1) arrived
                writeA(nxt);
            }
            if (p == 3) issueA(tp2);                               // vm: 4 -> 8

            __builtin_amdgcn_s_barrier();
            asm volatile("s_waitcnt lgkmcnt(0)" ::: "memory");
            __builtin_amdgcn_sched_barrier(0);
            __builtin_amdgcn_s_setprio(1);
#pragma unroll
            for (int mi = 0; mi < 4; ++mi)
#pragma unroll
                for (int ni = 0; ni < 2; ++ni) {
                    f32x4 a = acc[mh * 4 + mi][nh * 2 + ni];
                    a = __builtin_amdgcn_mfma_f32_16x16x32_bf16(fah[mi], fbh[ni], a, 0, 0, 0);
                    a = __builtin_amdgcn_mfma_f32_16x16x32_bf16(fal[mi], fbh[ni], a, 0, 0, 0);
                    a = __builtin_amdgcn_mfma_f32_16x16x32_bf16(fah[mi], fbl[ni], a, 0, 0, 0);
                    acc[mh * 4 + mi][nh * 2 + ni] = a;
                }
            __builtin_amdgcn_s_setprio(0);
            if (p < 3) {
                __builtin_amdgcn_s_barrier();
            } else {
                // boundary: force B(t+1) staged; leave A(t+2) loads in flight
                asm volatile("s_waitcnt vmcnt(4) lgkmcnt(0)" ::: "memory");
                __builtin_amdgcn_s_barrier();
            }
        }
    }

    // ---- epilogue: C/D layout col=lane&15, row=(lane>>4)*4+j ----
#pragma unroll
    for (int m = 0; m < 8; ++m)
#pragma unroll
        for (int n = 0; n < 4; ++n)
#pragma unroll
            for (int j = 0; j < 4; ++j) {
                const int row = row0 + wM * 128 + m * 16 + (lane >> 4) * 4 + j;
                const int col = col0 + wN * 64 + n * 16 + (lane & 15);
                float v = acc[m][n][j];
                if (EPI == 1) {
                    const int gate = col >> 10;
                    const int c = col & 1023;
                    const size_t ix = (size_t)row * UNITS + c;
                    if (gate == 0) {
                        outZ[ix] = tanhf(v + b0[c]);
                    } else if (gate == 1) {
                        Gws[ix] = tanhf(v + b1[c]);
                    } else {
                        SR[ix] = Sin[ix] * tanhf(v + b2[c]);
                    }
                } else {
                    const size_t ix = (size_t)row * UNITS + col;
                    float h = tanhf(v + b0[col]);
                    float z = outZ[ix];
                    float gg = Gws[ix];
                    float s = Sin[ix];
                    outZ[ix] = (1.0f - gg) * h + z * s;
                }
            }
}

extern "C" void kernel_launch(void* const* d_in, const int* in_sizes, int n_in,
                              void* d_out, int out_size, void* d_ws, size_t ws_size,
                              hipStream_t stream) {
    const float* X  = (const float*)d_in[0];
    const float* S  = (const float*)d_in[1];
    const float* Uz = (const float*)d_in[2];
    const float* Ug = (const float*)d_in[3];
    const float* Ur = (const float*)d_in[4];
    const float* Uh = (const float*)d_in[5];
    const float* Wz = (const float*)d_in[6];
    const float* Wg = (const float*)d_in[7];
    const float* Wr = (const float*)d_in[8];
    const float* Wh = (const float*)d_in[9];
    const float* bz = (const float*)d_in[10];
    const float* bg = (const float*)d_in[11];
    const float* br = (const float*)d_in[12];
    const float* bh = (const float*)d_in[13];
    float* out = (float*)d_out;

    // ws carve: 160 MiB total (same footprint that passed in round 2)
    const size_t SZ_PLANE = (size_t)NROWS * UNITS * 4;            // 64 MiB
    const size_t SZ_IMG1 = (size_t)12 * 64 * 8192 * 2;            // 12 MiB per plane
    const size_t SZ_IMG2 = (size_t)4 * 64 * 8192 * 2;             // 4 MiB per plane
    const size_t need = 2 * SZ_PLANE + 2 * SZ_IMG1 + 2 * SZ_IMG2;
    if (ws_size < need) return;

    char* wp = (char*)d_ws;
    float* SR = (float*)wp;  wp += SZ_PLANE;
    float* G  = (float*)wp;  wp += SZ_PLANE;
    unsigned short* img1H = (unsigned short*)wp; wp += SZ_IMG1;
    unsigned short* img1L = (unsigned short*)wp; wp += SZ_IMG1;
    unsigned short* img2H = (unsigned short*)wp; wp += SZ_IMG2;
    unsigned short* img2L = (unsigned short*)wp; wp += SZ_IMG2;

    // transient BT planes live in the SR region (overwritten later by GEMM1's SR output)
    char* sc = (char*)SR;
    const size_t W3 = (size_t)3072 * 1024 * 2;   // 6.29 MB
    const size_t W1 = (size_t)1024 * 1024 * 2;   // 2.10 MB
    unsigned short* BTU_h  = (unsigned short*)(sc);
    unsigned short* BTU_l  = (unsigned short*)(sc + W3);
    unsigned short* BTW_h  = (unsigned short*)(sc + 2 * W3);
    unsigned short* BTW_l  = (unsigned short*)(sc + 3 * W3);
    unsigned short* BTUh_h = (unsigned short*)(sc + 4 * W3);
    unsigned short* BTUh_l = (unsigned short*)(sc + 4 * W3 + W1);
    unsigned short* BTWh_h = (unsigned short*)(sc + 4 * W3 + 2 * W1);
    unsigned short* BTWh_l = (unsigned short*)(sc + 4 * W3 + 3 * W1);

    TrArgs ta;
    const size_t seg = (size_t)1024 * 1024;
    ta.src[0] = Uz; ta.dh[0] = BTU_h;            ta.dl[0] = BTU_l;
    ta.src[1] = Ug; ta.dh[1] = BTU_h + seg;      ta.dl[1] = BTU_l + seg;
    ta.src[2] = Ur; ta.dh[2] = BTU_h + 2 * seg;  ta.dl[2] = BTU_l + 2 * seg;
    ta.src[3] = Wz; ta.dh[3] = BTW_h;            ta.dl[3] = BTW_l;
    ta.src[4] = Wg; ta.dh[4] = BTW_h + seg;      ta.dl[4] = BTW_l + seg;
    ta.src[5] = Wr; ta.dh[5] = BTW_h + 2 * seg;  ta.dl[5] = BTW_l + 2 * seg;
    ta.src[6] = Uh; ta.dh[6] = BTUh_h;           ta.dl[6] = BTUh_l;
    ta.src[7] = Wh; ta.dh[7] = BTWh_h;           ta.dl[7] = BTWh_l;
    transpose_split<<<dim3(32, 32, 8), dim3(32, 8), 0, stream>>>(ta);

    img_perm_k<<<3072, 256, 0, stream>>>(BTU_h, BTU_l, BTW_h, BTW_l, img1H, img1L);
    img_perm_k<<<1024, 256, 0, stream>>>(BTUh_h, BTUh_l, BTWh_h, BTWh_l, img2H, img2L);

    // GEMM1: zgr = tanh(X@U_zgr + S@W_zgr + b); Z->out, G->ws, SR=S*tanh(R)->ws
    gemm8<1><<<768, 512, 0, stream>>>(X, S, img1H, img1L, S, bz, bg, br, out, G, SR);
    // GEMM2: H = tanh(X@Uh + SR@Wh + bh); S_new = (1-G)*H + Z*S
    gemm8<2><<<256, 512, 0, stream>>>(X, SR, img2H, img2L, S, bh, nullptr, nullptr, out, G, SR);
}

// Round 10
// 1096.727 us; speedup vs baseline: 1.1439x; 1.0220x over previous
//
#include <hip/hip_runtime.h>
#include <hip/hip_bf16.h>

typedef short short8 __attribute__((ext_vector_type(8)));
typedef unsigned short ushort8 __attribute__((ext_vector_type(8)));
typedef float f32x4 __attribute__((ext_vector_type(4)));

#define NROWS 16384
#define UNITS 1024

__device__ __forceinline__ unsigned short f2bf(float x) {
    union { float f; unsigned int u; } v; v.f = x;
    unsigned int r = v.u + 0x7fffu + ((v.u >> 16) & 1u);
    return (unsigned short)(r >> 16);
}
__device__ __forceinline__ float bf2f(unsigned short h) {
    union { unsigned int u; float f; } v; v.u = ((unsigned int)h) << 16; return v.f;
}

// ---------------- prep 1: transpose weights [K x N] -> BT [N x K], split bf16 hi/lo --------
struct TrArgs {
    const float* src[8];
    unsigned short* dh[8];
    unsigned short* dl[8];
};

__global__ void transpose_split(TrArgs args) {
    __shared__ float t[32][33];
    const float* src = args.src[blockIdx.z];
    unsigned short* dh = args.dh[blockIdx.z];
    unsigned short* dl = args.dl[blockIdx.z];
    const int tx = threadIdx.x, ty = threadIdx.y;
    const int bk = blockIdx.y * 32, bn = blockIdx.x * 32;
#pragma unroll
    for (int q = 0; q < 4; ++q)
        t[ty + q * 8][tx] = src[(size_t)(bk + ty + q * 8) * UNITS + bn + tx];
    __syncthreads();
#pragma unroll
    for (int q = 0; q < 4; ++q) {
        float v = t[tx][ty + q * 8];
        unsigned short h = f2bf(v);
        size_t o = (size_t)(bn + ty + q * 8) * UNITS + bk + tx;
        dh[o] = h;
        dl[o] = f2bf(v - bf2f(h));
    }
}

// ---------------- prep 2: build swizzled per-(colblock,ktile) staging images ----------------
// Image elem layout: [tile][c(256)][q'(4)][e(8)], holding BT[cb*256+c][k0 + (q'^((c>>1)&3))*8 + e].
// global_load_lds then copies image bytes linearly into LDS; reads apply the same XOR.
__global__ void img_perm_k(const unsigned short* __restrict__ BT0h, const unsigned short* __restrict__ BT0l,
                           const unsigned short* __restrict__ BT1h, const unsigned short* __restrict__ BT1l,
                           unsigned short* __restrict__ imgH, unsigned short* __restrict__ imgL) {
    const int g = blockIdx.x * blockDim.x + threadIdx.x;   // one 16B chunk per thread
    const int tile = g >> 10;
    const int c = (g >> 2) & 255;
    const int qp = g & 3;
    const int cb = tile >> 6, kt = tile & 63;
    const int col = cb * 256 + c;
    const int kin = (qp ^ ((c >> 1) & 3)) * 8;
    const unsigned short* sh;
    const unsigned short* sl;
    int k0;
    if (kt < 32) { sh = BT0h; sl = BT0l; k0 = kt * 32; }
    else         { sh = BT1h; sl = BT1l; k0 = (kt - 32) * 32; }
    const size_t so = (size_t)col * 1024 + k0 + kin;
    *reinterpret_cast<ushort8*>(imgH + (size_t)g * 8) = *reinterpret_cast<const ushort8*>(sh + so);
    *reinterpret_cast<ushort8*>(imgL + (size_t)g * 8) = *reinterpret_cast<const ushort8*>(sl + so);
}

// ---------------- main GEMM: 256x256 tile, BK=32, 8 waves, 4-phase counted-vmcnt pipeline ----
// C = [A0|A1](fp32) @ B^T via bf16 hi/lo 3-term split. B from pre-swizzled images.
// Round 9: (1) consecutive blocks share the A row-panel (rb) so X/S hit L2/L3;
//          (2) non-temporal epilogue stores keep the 192MB write stream out of L3.
template <int EPI>
__global__ __launch_bounds__(512, 2) void gemm8(
    const float* __restrict__ A0, const float* __restrict__ A1,
    const unsigned short* __restrict__ imgH, const unsigned short* __restrict__ imgL,
    const float* __restrict__ Sin,
    const float* __restrict__ b0, const float* __restrict__ b1, const float* __restrict__ b2,
    float* __restrict__ outZ, float* __restrict__ Gws, float* __restrict__ SR) {
    // LDS: 2 buffers x {Ah,Al,Bh,Bl} x 16 KB = 128 KiB
    __shared__ __align__(16) char lds[131072];

    const int tid = threadIdx.x;
    const int wave = tid >> 6, lane = tid & 63;
    const int wM = wave >> 2, wN = wave & 3;          // 2 x 4 wave grid; wave owns 128x64
    const int fr = lane & 15, fq = lane >> 4;
    const int sA = ((fq ^ ((fr >> 1) & 3)) << 4);     // swizzled chunk byte offset (read side)
    const int arow = tid >> 1, ahalf = tid & 1;       // A staging: 2 threads/row
    const int awsz = (tid >> 2) & 3;                  // (arow>>1)&3

    // XCD-aware block swizzle (grid % 8 == 0; chunk per XCD = nwg/8, NCB | chunk)
    const int nwg = gridDim.x;
    const int w = (blockIdx.x & 7) * (nwg >> 3) + (blockIdx.x >> 3);
    constexpr int NCB = (EPI == 1) ? 12 : 4;          // col-blocks per row-panel group
    const int rb = w / NCB;                            // consecutive w share rb (A panel)
    const int cb = w - rb * NCB;
    const int row0 = rb * 256;
    const int col0 = cb * 256;

    f32x4 acc[8][4] = {};
    float4 av[4];                   // in-flight A fp32 regs (one tile)

    auto issueA = [&](int ts) {
        const float* Ag = (ts < 32 ? A0 : A1) + (size_t)(row0 + arow) * 1024 + (ts & 31) * 32 + ahalf * 16;
        av[0] = *reinterpret_cast<const float4*>(Ag);
        av[1] = *reinterpret_cast<const float4*>(Ag + 4);
        av[2] = *reinterpret_cast<const float4*>(Ag + 8);
        av[3] = *reinterpret_cast<const float4*>(Ag + 12);
    };
    auto issueB = [&](int ts, int buf, int pl) {      // 2 gload_lds per wave per plane
        const unsigned short* img = (pl ? imgL : imgH) + ((size_t)(cb * 64 + ts)) * 8192;
#pragma unroll
        for (int i = 0; i < 2; ++i) {
            const unsigned short* src = img + (wave * 2 + i) * 512 + lane * 8;
            char* dst = lds + (buf << 16) + 32768 + pl * 16384 + (wave * 2 + i) * 1024;
            __builtin_amdgcn_global_load_lds(
                (const __attribute__((address_space(1))) unsigned int*)src,
                (__attribute__((address_space(3))) unsigned int*)dst, 16, 0, 0);
        }
    };
    auto writeA = [&](int buf) {                      // cvt fp32 -> hi/lo, swizzled ds_write
        ushort8 h0, h1, l0, l1;
#pragma unroll
        for (int j = 0; j < 2; ++j) {
            float4 v = av[j];
            h0[j * 4 + 0] = f2bf(v.x); l0[j * 4 + 0] = f2bf(v.x - bf2f(h0[j * 4 + 0]));
            h0[j * 4 + 1] = f2bf(v.y); l0[j * 4 + 1] = f2bf(v.y - bf2f(h0[j * 4 + 1]));
            h0[j * 4 + 2] = f2bf(v.z); l0[j * 4 + 2] = f2bf(v.z - bf2f(h0[j * 4 + 2]));
            h0[j * 4 + 3] = f2bf(v.w); l0[j * 4 + 3] = f2bf(v.w - bf2f(h0[j * 4 + 3]));
        }
#pragma unroll
        for (int j = 0; j < 2; ++j) {
            float4 v = av[2 + j];
            h1[j * 4 + 0] = f2bf(v.x); l1[j * 4 + 0] = f2bf(v.x - bf2f(h1[j * 4 + 0]));
            h1[j * 4 + 1] = f2bf(v.y); l1[j * 4 + 1] = f2bf(v.y - bf2f(h1[j * 4 + 1]));
            h1[j * 4 + 2] = f2bf(v.z); l1[j * 4 + 2] = f2bf(v.z - bf2f(h1[j * 4 + 2]));
            h1[j * 4 + 3] = f2bf(v.w); l1[j * 4 + 3] = f2bf(v.w - bf2f(h1[j * 4 + 3]));
        }
        const int q0 = (2 * ahalf) ^ awsz;
        const int q1 = (2 * ahalf + 1) ^ awsz;
        char* db = lds + (buf << 16) + arow * 64;
        *reinterpret_cast<ushort8*>(db + (q0 << 4)) = h0;
        *reinterpret_cast<ushort8*>(db + (q1 << 4)) = h1;
        *reinterpret_cast<ushort8*>(db + 16384 + (q0 << 4)) = l0;
        *reinterpret_cast<ushort8*>(db + 16384 + (q1 << 4)) = l1;
    };

    // ---- prologue: stage tile 0, issue A(1); leaves [A(1):4] in flight ----
    issueA(0);
    issueB(0, 0, 0);
    issueB(0, 0, 1);
    asm volatile("s_waitcnt vmcnt(4)" ::: "memory");   // A(0) arrived (B(0) in flight)
    writeA(0);
    issueA(1);
    asm volatile("s_waitcnt vmcnt(4) lgkmcnt(0)" ::: "memory");  // B(0) done; A-writes drained
    __builtin_amdgcn_s_barrier();

    // ---- main loop: 64 K-tiles of 32 (K = 2x1024), 4 phases each ----
    for (int t = 0; t < 64; ++t) {
        const int cur = t & 1, nxt = cur ^ 1;
        const int tp1 = (t + 1 < 64) ? t + 1 : 0;      // dummy-alias tile 0 past the end
        const int tp2 = (t + 2 < 64) ? t + 2 : 0;
        const char* base = lds + (cur << 16);
#pragma unroll
        for (int p = 0; p < 4; ++p) {
            const int mh = p >> 1, nh = p & 1;         // C-quadrant
            short8 fah[4], fal[4], fbh[2], fbl[2];
#pragma unroll
            for (int mi = 0; mi < 4; ++mi) {
                const int off = (wM * 128 + (mh * 4 + mi) * 16 + fr) * 64 + sA;
                fah[mi] = *reinterpret_cast<const short8*>(base + off);
                fal[mi] = *reinterpret_cast<const short8*>(base + 16384 + off);
            }
#pragma unroll
            for (int ni = 0; ni < 2; ++ni) {
                const int off = (wN * 64 + (nh * 2 + ni) * 16 + fr) * 64 + sA;
                fbh[ni] = *reinterpret_cast<const short8*>(base + 32768 + off);
                fbl[ni] = *reinterpret_cast<const short8*>(base + 49152 + off);
            }
            // staging slice for this phase (counted-vmcnt ledger; see header comment)
            if (p == 0) issueB(tp1, nxt, 0);                       // vm: 4 -> 6
            if (p == 1) issueB(tp1, nxt, 1);                       // vm: 6 -> 8
            if (p == 2) {
                asm volatile("s_waitcnt vmcnt(4)" ::: "memory");   // A(t+1) arrived
                writeA(nxt);
            }
            if (p == 3) issueA(tp2);                               // vm: 4 -> 8

            __builtin_amdgcn_s_barrier();
            asm volatile("s_waitcnt lgkmcnt(0)" ::: "memory");
            __builtin_amdgcn_sched_barrier(0);
            __builtin_amdgcn_s_setprio(1);
#pragma unroll
            for (int mi = 0; mi < 4; ++mi)
#pragma unroll
                for (int ni = 0; ni < 2; ++ni) {
                    f32x4 a = acc[mh * 4 + mi][nh * 2 + ni];
                    a = __builtin_amdgcn_mfma_f32_16x16x32_bf16(fah[mi], fbh[ni], a, 0, 0, 0);
                    a = __builtin_amdgcn_mfma_f32_16x16x32_bf16(fal[mi], fbh[ni], a, 0, 0, 0);
                    a = __builtin_amdgcn_mfma_f32_16x16x32_bf16(fah[mi], fbl[ni], a, 0, 0, 0);
                    acc[mh * 4 + mi][nh * 2 + ni] = a;
                }
            __builtin_amdgcn_s_setprio(0);
            if (p < 3) {
                __builtin_amdgcn_s_barrier();
            } else {
                // boundary: force B(t+1) staged; leave A(t+2) loads in flight
                asm volatile("s_waitcnt vmcnt(4) lgkmcnt(0)" ::: "memory");
                __builtin_amdgcn_s_barrier();
            }
        }
    }

    // ---- epilogue: C/D layout col=lane&15, row=(lane>>4)*4+j; non-temporal stores ----
#pragma unroll
    for (int m = 0; m < 8; ++m)
#pragma unroll
        for (int n = 0; n < 4; ++n)
#pragma unroll
            for (int j = 0; j < 4; ++j) {
                const int row = row0 + wM * 128 + m * 16 + (lane >> 4) * 4 + j;
                const int col = col0 + wN * 64 + n * 16 + (lane & 15);
                float v = acc[m][n][j];
                if (EPI == 1) {
                    const int gate = col >> 10;
                    const int c = col & 1023;
                    const size_t ix = (size_t)row * UNITS + c;
                    if (gate == 0) {
                        __builtin_nontemporal_store(tanhf(v + b0[c]), &outZ[ix]);
                    } else if (gate == 1) {
                        __builtin_nontemporal_store(tanhf(v + b1[c]), &Gws[ix]);
                    } else {
                        __builtin_nontemporal_store(Sin[ix] * tanhf(v + b2[c]), &SR[ix]);
                    }
                } else {
                    const size_t ix = (size_t)row * UNITS + col;
                    float h = tanhf(v + b0[col]);
                    float z = __builtin_nontemporal_load(&outZ[ix]);
                    float gg = __builtin_nontemporal_load(&Gws[ix]);
                    float s = Sin[ix];
                    __builtin_nontemporal_store((1.0f - gg) * h + z * s, &outZ[ix]);
                }
            }
}

extern "C" void kernel_launch(void* const* d_in, const int* in_sizes, int n_in,
                              void* d_out, int out_size, void* d_ws, size_t ws_size,
                              hipStream_t stream) {
    const float* X  = (const float*)d_in[0];
    const float* S  = (const float*)d_in[1];
    const float* Uz = (const float*)d_in[2];
    const float* Ug = (const float*)d_in[3];
    const float* Ur = (const float*)d_in[4];
    const float* Uh = (const float*)d_in[5];
    const float* Wz = (const float*)d_in[6];
    const float* Wg = (const float*)d_in[7];
    const float* Wr = (const float*)d_in[8];
    const float* Wh = (const float*)d_in[9];
    const float* bz = (const float*)d_in[10];
    const float* bg = (const float*)d_in[11];
    const float* br = (const float*)d_in[12];
    const float* bh = (const float*)d_in[13];
    float* out = (float*)d_out;

    // ws carve: 160 MiB total (footprint proven in rounds 2 and 8)
    const size_t SZ_PLANE = (size_t)NROWS * UNITS * 4;            // 64 MiB
    const size_t SZ_IMG1 = (size_t)12 * 64 * 8192 * 2;            // 12 MiB per plane
    const size_t SZ_IMG2 = (size_t)4 * 64 * 8192 * 2;             // 4 MiB per plane
    const size_t need = 2 * SZ_PLANE + 2 * SZ_IMG1 + 2 * SZ_IMG2;
    if (ws_size < need) return;

    char* wp = (char*)d_ws;
    float* SR = (float*)wp;  wp += SZ_PLANE;
    float* G  = (float*)wp;  wp += SZ_PLANE;
    unsigned short* img1H = (unsigned short*)wp; wp += SZ_IMG1;
    unsigned short* img1L = (unsigned short*)wp; wp += SZ_IMG1;
    unsigned short* img2H = (unsigned short*)wp; wp += SZ_IMG2;
    unsigned short* img2L = (unsigned short*)wp; wp += SZ_IMG2;

    // transient BT planes live in the SR region (overwritten later by GEMM1's SR output)
    char* sc = (char*)SR;
    const size_t W3 = (size_t)3072 * 1024 * 2;   // 6.29 MB
    const size_t W1 = (size_t)1024 * 1024 * 2;   // 2.10 MB
    unsigned short* BTU_h  = (unsigned short*)(sc);
    unsigned short* BTU_l  = (unsigned short*)(sc + W3);
    unsigned short* BTW_h  = (unsigned short*)(sc + 2 * W3);
    unsigned short* BTW_l  = (unsigned short*)(sc + 3 * W3);
    unsigned short* BTUh_h = (unsigned short*)(sc + 4 * W3);
    unsigned short* BTUh_l = (unsigned short*)(sc + 4 * W3 + W1);
    unsigned short* BTWh_h = (unsigned short*)(sc + 4 * W3 + 2 * W1);
    unsigned short* BTWh_l = (unsigned short*)(sc + 4 * W3 + 3 * W1);

    TrArgs ta;
    const size_t seg = (size_t)1024 * 1024;
    ta.src[0] = Uz; ta.dh[0] = BTU_h;            ta.dl[0] = BTU_l;
    ta.src[1] = Ug; ta.dh[1] = BTU_h + seg;      ta.dl[1] = BTU_l + seg;
    ta.src[2] = Ur; ta.dh[2] = BTU_h + 2 * seg;  ta.dl[2] = BTU_l + 2 * seg;
    ta.src[3] = Wz; ta.dh[3] = BTW_h;            ta.dl[3] = BTW_l;
    ta.src[4] = Wg; ta.dh[4] = BTW_h + seg;      ta.dl[4] = BTW_l + seg;
    ta.src[5] = Wr; ta.dh[5] = BTW_h + 2 * seg;  ta.dl[5] = BTW_l + 2 * seg;
    ta.src[6] = Uh; ta.dh[6] = BTUh_h;           ta.dl[6] = BTUh_l;
    ta.src[7] = Wh; ta.dh[7] = BTWh_h;           ta.dl[7] = BTWh_l;
    transpose_split<<<dim3(32, 32, 8), dim3(32, 8), 0, stream>>>(ta);

    img_perm_k<<<3072, 256, 0, stream>>>(BTU_h, BTU_l, BTW_h, BTW_l, img1H, img1L);
    img_perm_k<<<1024, 256, 0, stream>>>(BTUh_h, BTUh_l, BTWh_h, BTWh_l, img2H, img2L);

    // GEMM1: zgr = tanh(X@U_zgr + S@W_zgr + b); Z->out, G->ws, SR=S*tanh(R)->ws
    gemm8<1><<<768, 512, 0, stream>>>(X, S, img1H, img1L, S, bz, bg, br, out, G, SR);
    // GEMM2: H = tanh(X@Uh + SR@Wh + bh); S_new = (1-G)*H + Z*S
    gemm8<2><<<256, 512, 0, stream>>>(X, SR, img2H, img2L, S, bh, nullptr, nullptr, out, G, SR);
}